// Round 16
// baseline (286.791 us; speedup 1.0000x reference)
//
#include <hip/hip_runtime.h>

#define EPS 1e-7f
#define CCH 42
#define NCON 8

typedef float v4f __attribute__((ext_vector_type(4)));
typedef float v2f __attribute__((ext_vector_type(2)));

__device__ __forceinline__ v2f ldw2(const float* __restrict__ p) {
    v2f w; __builtin_memcpy(&w, p, 8); return w;   // 4B-aligned safe
}

// ---------------------------------------------------------------------------
// Per-channel MLP (dims NIN -> 5 -> 4 -> 4 -> 3) + 3-way softmax.
// `c` is wave-uniform -> weight/bias reads are scalar (s_load).
// Dot products packed over the INPUT dim as v2f (v_pk_fma_f32): bias seeds
// the accumulator, one horizontal add per neuron, scalar tail for odd NIN.
// ---------------------------------------------------------------------------
template<int NIN>
__device__ __forceinline__ void mlp_softmax3(
    const float x[NIN], const v2f xp[NIN / 2], int c,
    const float* __restrict__ W0, const float* __restrict__ b0,
    const float* __restrict__ W1, const float* __restrict__ b1,
    const float* __restrict__ W2, const float* __restrict__ b2,
    const float* __restrict__ W3, const float* __restrict__ b3,
    float o[3])
{
    float h0[5];
#pragma unroll
    for (int j = 0; j < 5; ++j) {
        const float* w = W0 + (c * 5 + j) * NIN;
        v2f acc = {b0[c * 5 + j], 0.0f};
#pragma unroll
        for (int p = 0; p < NIN / 2; ++p)
            acc = __builtin_elementwise_fma(xp[p], ldw2(w + 2 * p), acc);
        float a = acc.x + acc.y;
        if (NIN & 1) a = fmaf(x[NIN - 1], w[NIN - 1], a);
        h0[j] = fmaxf(a, 0.0f);
    }
    v2f h0p[2] = {{h0[0], h0[1]}, {h0[2], h0[3]}};
    float h1[4];
#pragma unroll
    for (int j = 0; j < 4; ++j) {
        const float* w = W1 + (c * 4 + j) * 5;
        v2f acc = {b1[c * 4 + j], 0.0f};
        acc = __builtin_elementwise_fma(h0p[0], ldw2(w), acc);
        acc = __builtin_elementwise_fma(h0p[1], ldw2(w + 2), acc);
        float a = fmaf(h0[4], w[4], acc.x + acc.y);
        h1[j] = fmaxf(a, 0.0f);
    }
    v2f h1p[2] = {{h1[0], h1[1]}, {h1[2], h1[3]}};
    float h2[4];
#pragma unroll
    for (int j = 0; j < 4; ++j) {
        const float* w = W2 + (c * 4 + j) * 4;
        v2f acc = {b2[c * 4 + j], 0.0f};
        acc = __builtin_elementwise_fma(h1p[0], ldw2(w), acc);
        acc = __builtin_elementwise_fma(h1p[1], ldw2(w + 2), acc);
        h2[j] = fmaxf(acc.x + acc.y, 0.0f);
    }
    v2f h2p[2] = {{h2[0], h2[1]}, {h2[2], h2[3]}};
    float lg[3];
#pragma unroll
    for (int j = 0; j < 3; ++j) {
        const float* w = W3 + (c * 3 + j) * 4;
        v2f acc = {b3[c * 3 + j], 0.0f};
        acc = __builtin_elementwise_fma(h2p[0], ldw2(w), acc);
        acc = __builtin_elementwise_fma(h2p[1], ldw2(w + 2), acc);
        lg[j] = acc.x + acc.y;
    }
    float m = fmaxf(fmaxf(lg[0], lg[1]), lg[2]);
    float e0 = __expf(lg[0] - m);
    float e1 = __expf(lg[1] - m);
    float e2 = __expf(lg[2] - m);
    float r = __fdividef(1.0f, e0 + e1 + e2);
    o[0] = e0 * r;
    o[1] = e1 * r;
    o[2] = e2 * r;
}

// ---------------------------------------------------------------------------
// Fused kernel (R15 structure + packed-f32 MLP + v4f phase-B stores).
// grid = (N/64, 2). Block = 384 thr / 6 waves, 64 samples, one output slice
// + its own 1344-elem tau chunk. LDS 32256 B, launch_bounds (384,8)
// -> 5 blocks/CU = 30 waves (94%).
//   Pipeline: [scalars][tau 0-1] A  C1(consume 0-1; mu via __shfl)
//             [tau 2-3 issue] sync  B(flat v4f nt copy)  C2(consume 2-3).
// ---------------------------------------------------------------------------
__global__ __launch_bounds__(384, 8) void k_fused(
    const float* __restrict__ tau,
    const float* __restrict__ mu_direct,
    const float* __restrict__ mu_diffuse,
    const float* __restrict__ cons,
    const float* __restrict__ Wd0, const float* __restrict__ bd0,
    const float* __restrict__ Wf0, const float* __restrict__ bf0,
    const float* __restrict__ Wd1, const float* __restrict__ bd1,
    const float* __restrict__ Wf1, const float* __restrict__ bf1,
    const float* __restrict__ Wd2, const float* __restrict__ bd2,
    const float* __restrict__ Wf2, const float* __restrict__ bf2,
    const float* __restrict__ Wd3, const float* __restrict__ bd3,
    const float* __restrict__ Wf3, const float* __restrict__ bf3,
    float* __restrict__ out, int N)
{
    __shared__ __align__(16) float es[64 * 126];
    const int tid  = threadIdx.x;
    const int lane = tid & 63;
    const int wave = tid >> 6;
    const int n0   = blockIdx.x * 64;
    const int n    = n0 + lane;
    const bool direct = (blockIdx.y == 0);
    const size_t nctot = (size_t)N * CCH;

    const int per        = 32 * CCH;                 // 1344 elements per slice
    const int base_local = direct ? 0 : per;
    const int base_e     = n0 * CCH + base_local;

    // ---- scalar inputs (oldest in vmcnt order) ----
    float4 c0 = *(const float4*)(cons + (size_t)n * NCON);
    float4 c1 = *(const float4*)(cons + (size_t)n * NCON + 4);
    float mud_own = mu_direct[n];
    float muf_own = mu_diffuse[n];
    __builtin_amdgcn_sched_barrier(0);

    // ---- tau batches 0-1 (16 VGPR in flight during A) ----
    v4f ta0, tb0, ta1, tb1;
    {
        const v4f* t4 = (const v4f*)tau + ((size_t)base_e + tid) * 2;
        ta0 = t4[0]; tb0 = t4[1];
        const v4f* t5 = (const v4f*)tau + ((size_t)base_e + 384 + tid) * 2;
        ta1 = t5[0]; tb1 = t5[1];
    }
    __builtin_amdgcn_sched_barrier(0);

    // ---- Phase A: MLP -> es (flat stride 126) ----
    float x[9] = {c0.x, c0.y, c0.z, c0.w, c1.x, c1.y, c1.z, c1.w, 0.0f};
    if (direct) {
        float inv = __fdividef(1.0f, mud_own + EPS);
#pragma unroll
        for (int i = 0; i < 8; ++i) x[i] *= inv;
        x[8] = mud_own;
        v2f xp[4] = {{x[0], x[1]}, {x[2], x[3]}, {x[4], x[5]}, {x[6], x[7]}};
#pragma unroll 1
        for (int ci = 0; ci < 7; ++ci) {
            int c = __builtin_amdgcn_readfirstlane(wave * 7 + ci);
            float o[3];
            mlp_softmax3<9>(x, xp, c, Wd0, bd0, Wd1, bd1, Wd2, bd2, Wd3, bd3, o);
#pragma unroll
            for (int k = 0; k < 3; ++k) es[lane * 126 + c * 3 + k] = o[k];
        }
    } else {
        v2f xp[4] = {{x[0], x[1]}, {x[2], x[3]}, {x[4], x[5]}, {x[6], x[7]}};
#pragma unroll 1
        for (int ci = 0; ci < 7; ++ci) {
            int c = __builtin_amdgcn_readfirstlane(wave * 7 + ci);
            float o[3];
            mlp_softmax3<8>(x, xp, c, Wf0, bf0, Wf1, bf1, Wf2, bf2, Wf3, bf3, o);
#pragma unroll
            for (int k = 0; k < 3; ++k) es[lane * 126 + c * 3 + k] = o[k];
        }
    }

    // ---- C1: consume batches 0-1 (landed during A); mu via lane shuffle ----
    {
        int off = tid;                               // < 768 < per, no guard
        float s = ((ta0.x + ta0.y) + (ta0.z + ta0.w)) + ((tb0.x + tb0.y) + (tb0.z + tb0.w));
        int nnl = (base_local + off) / CCH;
        float md = __shfl(mud_own, nnl) + EPS;
        float mf = __shfl(muf_own, nnl) + EPS;
        int e = base_e + off;
        __builtin_nontemporal_store(__expf(__fdividef(-s, md)), out + e);
        __builtin_nontemporal_store(__expf(__fdividef(-s, mf)), out + nctot + e);
    }
    {
        int off = 384 + tid;
        float s = ((ta1.x + ta1.y) + (ta1.z + ta1.w)) + ((tb1.x + tb1.y) + (tb1.z + tb1.w));
        int nnl = (base_local + off) / CCH;
        float md = __shfl(mud_own, nnl) + EPS;
        float mf = __shfl(muf_own, nnl) + EPS;
        int e = base_e + off;
        __builtin_nontemporal_store(__expf(__fdividef(-s, md)), out + e);
        __builtin_nontemporal_store(__expf(__fdividef(-s, mf)), out + nctot + e);
    }

    // ---- issue tau batches 2-3 (guarded; latency hides under B's stores) ----
    v4f ta2, tb2, ta3, tb3;
    const bool b3act = (3 * 384 + tid) < per;        // batch 3 half-active
    {
        const v4f* p2 = (const v4f*)tau + ((size_t)base_e + 2 * 384 + tid) * 2;
        ta2 = p2[0]; tb2 = p2[1];
        if (b3act) {
            const v4f* p3 = (const v4f*)tau + ((size_t)base_e + 3 * 384 + tid) * 2;
            ta3 = p3[0]; tb3 = p3[1];
        }
    }
    __builtin_amdgcn_sched_barrier(0);
    __syncthreads();

    // ---- Phase B: flat contiguous v4f nt copy of the tile (2016 x 16 B) ----
    {
        float* base = out + (direct ? 2 : 5) * nctot + (size_t)n0 * (CCH * 3);
#pragma unroll
        for (int k = 0; k < 6; ++k) {
            int idx = k * 384 + tid;
            if (idx < 2016) {
                v4f v = ((const v4f*)es)[idx];
                __builtin_nontemporal_store(v, (v4f*)base + idx);
            }
        }
    }

    // ---- C2: consume batches 2-3 (older than B's stores: counted waits) ----
    {
        int off = 2 * 384 + tid;                     // < 1152 < per, no guard
        float s = ((ta2.x + ta2.y) + (ta2.z + ta2.w)) + ((tb2.x + tb2.y) + (tb2.z + tb2.w));
        int nnl = (base_local + off) / CCH;
        float md = __shfl(mud_own, nnl) + EPS;
        float mf = __shfl(muf_own, nnl) + EPS;
        int e = base_e + off;
        __builtin_nontemporal_store(__expf(__fdividef(-s, md)), out + e);
        __builtin_nontemporal_store(__expf(__fdividef(-s, mf)), out + nctot + e);
    }
    if (b3act) {
        int off = 3 * 384 + tid;
        float s = ((ta3.x + ta3.y) + (ta3.z + ta3.w)) + ((tb3.x + tb3.y) + (tb3.z + tb3.w));
        int nnl = (base_local + off) / CCH;
        float md = __shfl(mud_own, nnl) + EPS;
        float mf = __shfl(muf_own, nnl) + EPS;
        int e = base_e + off;
        __builtin_nontemporal_store(__expf(__fdividef(-s, md)), out + e);
        __builtin_nontemporal_store(__expf(__fdividef(-s, mf)), out + nctot + e);
    }
}

extern "C" void kernel_launch(void* const* d_in, const int* in_sizes, int n_in,
                              void* d_out, int out_size, void* d_ws, size_t ws_size,
                              hipStream_t stream) {
    const float* tau  = (const float*)d_in[0];
    const float* mud  = (const float*)d_in[1];
    const float* muf  = (const float*)d_in[2];
    const float* cons = (const float*)d_in[3];
    // setup_inputs() dict order: Wd{i}, bd{i}, Wf{i}, bf{i} interleaved per layer.
    const float* Wd0 = (const float*)d_in[4];  const float* bd0 = (const float*)d_in[5];
    const float* Wf0 = (const float*)d_in[6];  const float* bf0 = (const float*)d_in[7];
    const float* Wd1 = (const float*)d_in[8];  const float* bd1 = (const float*)d_in[9];
    const float* Wf1 = (const float*)d_in[10]; const float* bf1 = (const float*)d_in[11];
    const float* Wd2 = (const float*)d_in[12]; const float* bd2 = (const float*)d_in[13];
    const float* Wf2 = (const float*)d_in[14]; const float* bf2 = (const float*)d_in[15];
    const float* Wd3 = (const float*)d_in[16]; const float* bd3 = (const float*)d_in[17];
    const float* Wf3 = (const float*)d_in[18]; const float* bf3 = (const float*)d_in[19];
    float* out = (float*)d_out;

    int N = in_sizes[1];            // mu_direct element count = N
    dim3 grid(N / 64, 2);
    k_fused<<<grid, 384, 0, stream>>>(tau, mud, muf, cons,
                                      Wd0, bd0, Wf0, bf0,
                                      Wd1, bd1, Wf1, bf1,
                                      Wd2, bd2, Wf2, bf2,
                                      Wd3, bd3, Wf3, bf3,
                                      out, N);
}

// Round 17
// 283.240 us; speedup vs baseline: 1.0125x; 1.0125x over previous
//
#include <hip/hip_runtime.h>

#define EPS 1e-7f
#define CCH 42
#define NCON 8

typedef float v4f __attribute__((ext_vector_type(4)));
typedef float v2f __attribute__((ext_vector_type(2)));

// ---------------------------------------------------------------------------
// Per-channel MLP (dims NIN -> 5 -> 4 -> 4 -> 3) + 3-way softmax.
// `c` is wave-uniform, so weight/bias loads compile to s_load and FMAs take
// the weight operand from SGPRs.
// ---------------------------------------------------------------------------
template<int NIN>
__device__ __forceinline__ void mlp_softmax3(
    const float x[NIN], int c,
    const float* __restrict__ W0, const float* __restrict__ b0,
    const float* __restrict__ W1, const float* __restrict__ b1,
    const float* __restrict__ W2, const float* __restrict__ b2,
    const float* __restrict__ W3, const float* __restrict__ b3,
    float o[3])
{
    float h0[5];
#pragma unroll
    for (int j = 0; j < 5; ++j) {
        const float* w = W0 + (c * 5 + j) * NIN;
        float a = b0[c * 5 + j];
#pragma unroll
        for (int i = 0; i < NIN; ++i) a = fmaf(x[i], w[i], a);
        h0[j] = fmaxf(a, 0.0f);
    }
    float h1[4];
#pragma unroll
    for (int j = 0; j < 4; ++j) {
        const float* w = W1 + (c * 4 + j) * 5;
        float a = b1[c * 4 + j];
#pragma unroll
        for (int i = 0; i < 5; ++i) a = fmaf(h0[i], w[i], a);
        h1[j] = fmaxf(a, 0.0f);
    }
    float h2[4];
#pragma unroll
    for (int j = 0; j < 4; ++j) {
        const float* w = W2 + (c * 4 + j) * 4;
        float a = b2[c * 4 + j];
#pragma unroll
        for (int i = 0; i < 4; ++i) a = fmaf(h1[i], w[i], a);
        h2[j] = fmaxf(a, 0.0f);
    }
    float lg[3];
#pragma unroll
    for (int j = 0; j < 3; ++j) {
        const float* w = W3 + (c * 3 + j) * 4;
        float a = b3[c * 3 + j];
#pragma unroll
        for (int i = 0; i < 4; ++i) a = fmaf(h2[i], w[i], a);
        lg[j] = a;
    }
    float m = fmaxf(fmaxf(lg[0], lg[1]), lg[2]);
    float e0 = __expf(lg[0] - m);
    float e1 = __expf(lg[1] - m);
    float e2 = __expf(lg[2] - m);
    float r = __fdividef(1.0f, e0 + e1 + e2);
    o[0] = e0 * r;
    o[1] = e1 * r;
    o[2] = e2 * r;
}

// ---------------------------------------------------------------------------
// Fused kernel, occupancy-tuned (R15 champion, reverted from R16's neutral
// packing). grid = (N/64, 2). Block = 384 thr / 6 waves, 64 samples, one
// output slice + its own 1344-elem tau chunk.
//   VGPR <= 64 (launch_bounds (384,8)) + LDS 32256 B (stride-126 flat tile)
//   -> 5 blocks/CU = 30 waves (94%).
//   Pipeline: [scalars][tau 0-1] A  C1(consume 0-1; mu via __shfl)
//             [tau 2-3 issue] sync  B(flat v2f nt copy)  C2(consume 2-3).
//   vmcnt in-order: C2's tau loads are older than B's stores -> counted
//   wait, never drains the store burst. nt stores (write-once, bypass L2:
//   R11 showed plain stores cost +21us); plain tau loads (L2 aggregates:
//   R12 beat nt loads).
// ---------------------------------------------------------------------------
__global__ __launch_bounds__(384, 8) void k_fused(
    const float* __restrict__ tau,
    const float* __restrict__ mu_direct,
    const float* __restrict__ mu_diffuse,
    const float* __restrict__ cons,
    const float* __restrict__ Wd0, const float* __restrict__ bd0,
    const float* __restrict__ Wf0, const float* __restrict__ bf0,
    const float* __restrict__ Wd1, const float* __restrict__ bd1,
    const float* __restrict__ Wf1, const float* __restrict__ bf1,
    const float* __restrict__ Wd2, const float* __restrict__ bd2,
    const float* __restrict__ Wf2, const float* __restrict__ bf2,
    const float* __restrict__ Wd3, const float* __restrict__ bd3,
    const float* __restrict__ Wf3, const float* __restrict__ bf3,
    float* __restrict__ out, int N)
{
    __shared__ __align__(16) float es[64 * 126];
    const int tid  = threadIdx.x;
    const int lane = tid & 63;
    const int wave = tid >> 6;
    const int n0   = blockIdx.x * 64;
    const int n    = n0 + lane;
    const bool direct = (blockIdx.y == 0);
    const size_t nctot = (size_t)N * CCH;

    const int per        = 32 * CCH;                 // 1344 elements per slice
    const int base_local = direct ? 0 : per;
    const int base_e     = n0 * CCH + base_local;

    // ---- scalar inputs (oldest in vmcnt order) ----
    float4 c0 = *(const float4*)(cons + (size_t)n * NCON);
    float4 c1 = *(const float4*)(cons + (size_t)n * NCON + 4);
    float mud_own = mu_direct[n];
    float muf_own = mu_diffuse[n];
    __builtin_amdgcn_sched_barrier(0);

    // ---- tau batches 0-1 (16 VGPR in flight during A) ----
    v4f ta0, tb0, ta1, tb1;
    {
        const v4f* t4 = (const v4f*)tau + ((size_t)base_e + tid) * 2;
        ta0 = t4[0]; tb0 = t4[1];
        const v4f* t5 = (const v4f*)tau + ((size_t)base_e + 384 + tid) * 2;
        ta1 = t5[0]; tb1 = t5[1];
    }
    __builtin_amdgcn_sched_barrier(0);

    // ---- Phase A: MLP -> es (flat stride 126) ----
    float x[9] = {c0.x, c0.y, c0.z, c0.w, c1.x, c1.y, c1.z, c1.w, 0.0f};
    if (direct) {
        float inv = __fdividef(1.0f, mud_own + EPS);
#pragma unroll
        for (int i = 0; i < 8; ++i) x[i] *= inv;
        x[8] = mud_own;
#pragma unroll 1
        for (int ci = 0; ci < 7; ++ci) {
            int c = __builtin_amdgcn_readfirstlane(wave * 7 + ci);
            float o[3];
            mlp_softmax3<9>(x, c, Wd0, bd0, Wd1, bd1, Wd2, bd2, Wd3, bd3, o);
#pragma unroll
            for (int k = 0; k < 3; ++k) es[lane * 126 + c * 3 + k] = o[k];
        }
    } else {
#pragma unroll 1
        for (int ci = 0; ci < 7; ++ci) {
            int c = __builtin_amdgcn_readfirstlane(wave * 7 + ci);
            float o[3];
            mlp_softmax3<8>(x, c, Wf0, bf0, Wf1, bf1, Wf2, bf2, Wf3, bf3, o);
#pragma unroll
            for (int k = 0; k < 3; ++k) es[lane * 126 + c * 3 + k] = o[k];
        }
    }

    // ---- C1: consume batches 0-1 (landed during A); mu via lane shuffle ----
    {
        int off = tid;                               // < 768 < per, no guard
        float s = ((ta0.x + ta0.y) + (ta0.z + ta0.w)) + ((tb0.x + tb0.y) + (tb0.z + tb0.w));
        int nnl = (base_local + off) / CCH;
        float md = __shfl(mud_own, nnl) + EPS;
        float mf = __shfl(muf_own, nnl) + EPS;
        int e = base_e + off;
        __builtin_nontemporal_store(__expf(__fdividef(-s, md)), out + e);
        __builtin_nontemporal_store(__expf(__fdividef(-s, mf)), out + nctot + e);
    }
    {
        int off = 384 + tid;
        float s = ((ta1.x + ta1.y) + (ta1.z + ta1.w)) + ((tb1.x + tb1.y) + (tb1.z + tb1.w));
        int nnl = (base_local + off) / CCH;
        float md = __shfl(mud_own, nnl) + EPS;
        float mf = __shfl(muf_own, nnl) + EPS;
        int e = base_e + off;
        __builtin_nontemporal_store(__expf(__fdividef(-s, md)), out + e);
        __builtin_nontemporal_store(__expf(__fdividef(-s, mf)), out + nctot + e);
    }

    // ---- issue tau batches 2-3 (guarded; latency hides under B's stores) ----
    v4f ta2, tb2, ta3, tb3;
    const bool b3act = (3 * 384 + tid) < per;        // batch 3 half-active
    {
        const v4f* p2 = (const v4f*)tau + ((size_t)base_e + 2 * 384 + tid) * 2;
        ta2 = p2[0]; tb2 = p2[1];
        if (b3act) {
            const v4f* p3 = (const v4f*)tau + ((size_t)base_e + 3 * 384 + tid) * 2;
            ta3 = p3[0]; tb3 = p3[1];
        }
    }
    __builtin_amdgcn_sched_barrier(0);
    __syncthreads();

    // ---- Phase B: flat contiguous v2f nt copy of the tile (4032 x 8 B) ----
    {
        float* base = out + (direct ? 2 : 5) * nctot + (size_t)n0 * (CCH * 3);
#pragma unroll
        for (int k = 0; k < 11; ++k) {
            int idx = k * 384 + tid;
            if (idx < 4032) {
                v2f v = ((const v2f*)es)[idx];
                __builtin_nontemporal_store(v, (v2f*)base + idx);
            }
        }
    }

    // ---- C2: consume batches 2-3 (older than B's stores: counted waits) ----
    {
        int off = 2 * 384 + tid;                     // < 1152 < per, no guard
        float s = ((ta2.x + ta2.y) + (ta2.z + ta2.w)) + ((tb2.x + tb2.y) + (tb2.z + tb2.w));
        int nnl = (base_local + off) / CCH;
        float md = __shfl(mud_own, nnl) + EPS;
        float mf = __shfl(muf_own, nnl) + EPS;
        int e = base_e + off;
        __builtin_nontemporal_store(__expf(__fdividef(-s, md)), out + e);
        __builtin_nontemporal_store(__expf(__fdividef(-s, mf)), out + nctot + e);
    }
    if (b3act) {
        int off = 3 * 384 + tid;
        float s = ((ta3.x + ta3.y) + (ta3.z + ta3.w)) + ((tb3.x + tb3.y) + (tb3.z + tb3.w));
        int nnl = (base_local + off) / CCH;
        float md = __shfl(mud_own, nnl) + EPS;
        float mf = __shfl(muf_own, nnl) + EPS;
        int e = base_e + off;
        __builtin_nontemporal_store(__expf(__fdividef(-s, md)), out + e);
        __builtin_nontemporal_store(__expf(__fdividef(-s, mf)), out + nctot + e);
    }
}

extern "C" void kernel_launch(void* const* d_in, const int* in_sizes, int n_in,
                              void* d_out, int out_size, void* d_ws, size_t ws_size,
                              hipStream_t stream) {
    const float* tau  = (const float*)d_in[0];
    const float* mud  = (const float*)d_in[1];
    const float* muf  = (const float*)d_in[2];
    const float* cons = (const float*)d_in[3];
    // setup_inputs() dict order: Wd{i}, bd{i}, Wf{i}, bf{i} interleaved per layer.
    const float* Wd0 = (const float*)d_in[4];  const float* bd0 = (const float*)d_in[5];
    const float* Wf0 = (const float*)d_in[6];  const float* bf0 = (const float*)d_in[7];
    const float* Wd1 = (const float*)d_in[8];  const float* bd1 = (const float*)d_in[9];
    const float* Wf1 = (const float*)d_in[10]; const float* bf1 = (const float*)d_in[11];
    const float* Wd2 = (const float*)d_in[12]; const float* bd2 = (const float*)d_in[13];
    const float* Wf2 = (const float*)d_in[14]; const float* bf2 = (const float*)d_in[15];
    const float* Wd3 = (const float*)d_in[16]; const float* bd3 = (const float*)d_in[17];
    const float* Wf3 = (const float*)d_in[18]; const float* bf3 = (const float*)d_in[19];
    float* out = (float*)d_out;

    int N = in_sizes[1];            // mu_direct element count = N
    dim3 grid(N / 64, 2);
    k_fused<<<grid, 384, 0, stream>>>(tau, mud, muf, cons,
                                      Wd0, bd0, Wf0, bf0,
                                      Wd1, bd1, Wf1, bf1,
                                      Wd2, bd2, Wf2, bf2,
                                      Wd3, bd3, Wf3, bf3,
                                      out, N);
}